// Round 6
// baseline (149.205 us; speedup 1.0000x reference)
//
#include <hip/hip_runtime.h>

// TemporalShift, residual mode == pure shift:
// x: (B=8, T=16, C=256, H=56, W=56) float32 contiguous.
// out[b,t,c] = x[b,t-1,c]  for c in [0,16)   (0 at t=0)
//            = x[b,t+1,c]  for c in [16,32)  (0 at t=15)
//            = x[b,t,c]    for c >= 32
//
// float4 view: 784 f4/plane, 200704 f4/time-step, 25,690,112 f4 total
//            = 100352 segments of 256 f4 (each segment uniform in class,t).
//
// R5 = R4 + two ADJACENT segments per block (50176 blocks): each thread
// issues 2 independent 16B loads (4KB apart) then 2 stores — vmcnt(1)
// staging amortizes the read->write turnaround while keeping the linear
// dispatcher-driven sweep that made R4 fast. All classification SALU.

typedef float f4 __attribute__((ext_vector_type(4)));

#define TS_CHW4   200704           // f4 per time step
#define NSEG      100352u          // 25,690,112 / 256

__device__ __forceinline__ void classify(unsigned seg, bool& zero, int& d) {
    const unsigned bt = seg / 784u;                  // b*16 + t (magic-mul, SALU)
    const unsigned r  = seg - bt * 784u;
    const unsigned t  = bt & 15u;
    const bool fwd  = r < 49u;                       // channels [0,16)
    const bool bwd  = !fwd && r < 98u;               // channels [16,32)
    zero = (fwd && t == 0u) || (bwd && t == 15u);
    d    = fwd ? -TS_CHW4 : (bwd ? TS_CHW4 : 0);
}

__global__ __launch_bounds__(256) void
ts_kernel(const f4* __restrict__ x, f4* __restrict__ out) {
    const unsigned seg0 = blockIdx.x * 2u;           // two adjacent segments
    const unsigned seg1 = seg0 + 1u;

    bool z0, z1; int d0, d1;
    classify(seg0, z0, d0);
    classify(seg1, z1, d1);

    const unsigned i0 = seg0 * 256u + threadIdx.x;
    const unsigned i1 = seg1 * 256u + threadIdx.x;

    // Issue both loads before either store (vmcnt staging).
    f4 v0 = (f4){0.f, 0.f, 0.f, 0.f};
    f4 v1 = (f4){0.f, 0.f, 0.f, 0.f};
    if (!z0) v0 = x[(unsigned)((int)i0 + d0)];
    if (!z1) v1 = x[(unsigned)((int)i1 + d1)];
    out[i0] = v0;
    out[i1] = v1;
}

extern "C" void kernel_launch(void* const* d_in, const int* in_sizes, int n_in,
                              void* d_out, int out_size, void* d_ws, size_t ws_size,
                              hipStream_t stream) {
    const f4* x = (const f4*)d_in[0];
    f4* out = (f4*)d_out;
    ts_kernel<<<NSEG / 2u, 256, 0, stream>>>(x, out); // 50176 blocks, zero tail
}

// Round 7
// 139.031 us; speedup vs baseline: 1.0732x; 1.0732x over previous
//
#include <hip/hip_runtime.h>

// TemporalShift, residual mode == pure shift:
// x: (B=8, T=16, C=256, H=56, W=56) float32 contiguous.
// out[b,t,c] = x[b,t-1,c]  for c in [0,16)   (0 at t=0)
//            = x[b,t+1,c]  for c in [16,32)  (0 at t=15)
//            = x[b,t,c]    for c >= 32
//
// float4 view: 784 f4/plane, 200704 f4/time-step, 25,690,112 f4 total
//            = 100352 segments of 256 f4 (each segment uniform in class,t).
//
// R6 = exact revert to R4 (best: 140.6 us = 5.85 TB/s = 93% of the 6.29 TB/s
// float4-copy ceiling). One f4 per thread, one segment per block; all shift
// logic SALU on the uniform blockIdx; each wave issues exactly 1 load + 1
// store. A/B history: 7-deep batch (R2) and 2-deep batch (R5) both REGRESS —
// per-wave issue depth 1 + dispatcher-driven linear sweep is the optimum.

typedef float f4 __attribute__((ext_vector_type(4)));

#define TS_CHW4   200704           // f4 per time step
#define NSEG      100352u          // 25,690,112 / 256

__global__ __launch_bounds__(256) void
ts_kernel(const f4* __restrict__ x, f4* __restrict__ out) {
    const unsigned seg = blockIdx.x;                 // one 256-f4 segment
    // Block-uniform (SALU) classification:
    const unsigned bt = seg / 784u;                  // b*16 + t
    const unsigned r  = seg - bt * 784u;             // 256-f4 segment within (b,t)
    const unsigned t  = bt & 15u;
    const bool fwd  = r < 49u;                       // channels [0,16)
    const bool bwd  = !fwd && r < 98u;               // channels [16,32)
    const bool zero = (fwd && t == 0u) || (bwd && t == 15u);
    const int  d    = fwd ? -TS_CHW4 : (bwd ? TS_CHW4 : 0);

    const unsigned i = seg * 256u + threadIdx.x;     // this thread's f4
    f4 v = (f4){0.f, 0.f, 0.f, 0.f};
    if (!zero) {                                     // uniform branch
        v = x[(unsigned)((int)i + d)];
    }
    out[i] = v;
}

extern "C" void kernel_launch(void* const* d_in, const int* in_sizes, int n_in,
                              void* d_out, int out_size, void* d_ws, size_t ws_size,
                              hipStream_t stream) {
    const f4* x = (const f4*)d_in[0];
    f4* out = (f4*)d_out;
    ts_kernel<<<NSEG, 256, 0, stream>>>(x, out);     // 100352 blocks, zero tail
}